// Round 1
// baseline (10227.419 us; speedup 1.0000x reference)
//
#include <hip/hip_runtime.h>

// AttnHGCN.forward_ui — 3-layer bipartite LightGCN-style propagation.
// Inputs: [0] layers_num (scalar int, ==3, hardcoded), [1] user_emb (100000x64 f32),
//         [2] item_emb (50000x64 f32), [3] inter_edge (2x2000000 i32, row0=u_idx,
//         row1=i_idx), [4] inter_edge_w (2000000 f32).
// Output: concat(item_acc*0.25 [50000x64], user_acc*0.25 [100000x64]) f32.

constexpr int N_USERS = 100000;
constexpr int N_ITEMS = 50000;
constexpr int CH      = 64;
constexpr int N_EDGES = 2000000;
constexpr int LAYERS  = 3;

constexpr long long ITEM_ELEMS = (long long)N_ITEMS * CH;  // 3,200,000
constexpr long long USER_ELEMS = (long long)N_USERS * CH;  // 6,400,000
constexpr long long TOT_ELEMS  = ITEM_ELEMS + USER_ELEMS;  // 9,600,000

// 16 lanes per edge; each lane owns a float4 (4 channels) of the 64-ch row.
// Gathers are coalesced 256B bursts from the gathered row; scatter via HW
// fp32 global atomics (unsafeAtomicAdd -> global_atomic_add_f32).
__global__ __launch_bounds__(256) void scatter_kernel(
    const float* __restrict__ src,   // [it_src (3.2M) | u_src (6.4M)]
    float* __restrict__ dst,         // [it_dst | u_dst], pre-zeroed
    const int* __restrict__ u_idx,
    const int* __restrict__ i_idx,
    const float* __restrict__ w) {
  long long tid = (long long)blockIdx.x * blockDim.x + threadIdx.x;
  int edge = (int)(tid >> 4);
  if (edge >= N_EDGES) return;
  int c = ((int)tid & 15) * 4;

  int   ui = u_idx[edge];
  int   ii = i_idx[edge];
  float we = w[edge];

  const float* it_src = src;
  const float* u_src  = src + ITEM_ELEMS;
  float*       it_dst = dst;
  float*       u_dst  = dst + ITEM_ELEMS;

  float4 itv = *(const float4*)(it_src + (long long)ii * CH + c);
  float4 uv  = *(const float4*)(u_src  + (long long)ui * CH + c);

  float* ud = u_dst  + (long long)ui * CH + c;
  float* id = it_dst + (long long)ii * CH + c;

  unsafeAtomicAdd(ud + 0, we * itv.x);
  unsafeAtomicAdd(ud + 1, we * itv.y);
  unsafeAtomicAdd(ud + 2, we * itv.z);
  unsafeAtomicAdd(ud + 3, we * itv.w);

  unsafeAtomicAdd(id + 0, we * uv.x);
  unsafeAtomicAdd(id + 1, we * uv.y);
  unsafeAtomicAdd(id + 2, we * uv.z);
  unsafeAtomicAdd(id + 3, we * uv.w);
}

// acc = (acc + add) * s   (s=1 for inner layers, 0.25 fused on the last)
__global__ __launch_bounds__(256) void add_scale_kernel(
    float* __restrict__ acc, const float* __restrict__ add, float s, long long n4) {
  long long i = (long long)blockIdx.x * blockDim.x + threadIdx.x;
  if (i >= n4) return;
  float4 a = ((const float4*)acc)[i];
  float4 b = ((const float4*)add)[i];
  a.x = (a.x + b.x) * s;
  a.y = (a.y + b.y) * s;
  a.z = (a.z + b.z) * s;
  a.w = (a.w + b.w) * s;
  ((float4*)acc)[i] = a;
}

extern "C" void kernel_launch(void* const* d_in, const int* in_sizes, int n_in,
                              void* d_out, int out_size, void* d_ws, size_t ws_size,
                              hipStream_t stream) {
  const float* user_emb = (const float*)d_in[1];
  const float* item_emb = (const float*)d_in[2];
  const int*   edges    = (const int*)d_in[3];
  const int*   u_idx    = edges;            // row 0
  const int*   i_idx    = edges + N_EDGES;  // row 1
  const float* w        = (const float*)d_in[4];

  float* out   = (float*)d_out;        // [item_acc | user_acc]
  float* buf_a = (float*)d_ws;         // [it | u]
  float* buf_b = buf_a + TOT_ELEMS;    // needs 76.8 MB of ws total

  const size_t item_bytes = (size_t)ITEM_ELEMS * sizeof(float);
  const size_t user_bytes = (size_t)USER_ELEMS * sizeof(float);

  // layer-0 source = input embeddings; accumulators start at input embeddings
  hipMemcpyAsync(buf_a,              item_emb, item_bytes, hipMemcpyDeviceToDevice, stream);
  hipMemcpyAsync(buf_a + ITEM_ELEMS, user_emb, user_bytes, hipMemcpyDeviceToDevice, stream);
  hipMemcpyAsync(out,                item_emb, item_bytes, hipMemcpyDeviceToDevice, stream);
  hipMemcpyAsync(out + ITEM_ELEMS,   user_emb, user_bytes, hipMemcpyDeviceToDevice, stream);

  const long long scatter_threads = (long long)N_EDGES * 16;  // 32M
  const int scatter_blocks = (int)((scatter_threads + 255) / 256);
  const long long n4 = TOT_ELEMS / 4;  // 2.4M float4s
  const int add_blocks = (int)((n4 + 255) / 256);

  float* src = buf_a;
  float* dst = buf_b;
  for (int l = 0; l < LAYERS; ++l) {
    hipMemsetAsync(dst, 0, (size_t)TOT_ELEMS * sizeof(float), stream);
    scatter_kernel<<<scatter_blocks, 256, 0, stream>>>(src, dst, u_idx, i_idx, w);
    const float s = (l == LAYERS - 1) ? (1.0f / (LAYERS + 1)) : 1.0f;
    add_scale_kernel<<<add_blocks, 256, 0, stream>>>(out, dst, s, n4);
    float* t = src; src = dst; dst = t;
  }
}

// Round 2
// 1027.428 us; speedup vs baseline: 9.9544x; 9.9544x over previous
//
#include <hip/hip_runtime.h>

// AttnHGCN.forward_ui — 3-layer bipartite LightGCN-style propagation.
// R2: replace per-layer fp32 atomic scatter (4 GB HBM writeback/layer, atomic-
// bound) with a once-per-call CSR build (counting sort by destination) + per-
// layer gather-sum (wave per destination row, zero atomics in the hot path).

constexpr int N_USERS = 100000;
constexpr int N_ITEMS = 50000;
constexpr int CH      = 64;
constexpr int N_EDGES = 2000000;
constexpr int LAYERS  = 3;
constexpr int NROWS   = N_USERS + N_ITEMS;          // 150000 combined dest rows
constexpr int NDIR    = 2 * N_EDGES;                // 4M directed edges

constexpr long long ITEM_ELEMS = (long long)N_ITEMS * CH;  // 3,200,000
constexpr long long USER_ELEMS = (long long)N_USERS * CH;  // 6,400,000
constexpr long long TOT_ELEMS  = ITEM_ELEMS + USER_ELEMS;  // 9,600,000

// ---------------- CSR build ----------------

__global__ __launch_bounds__(256) void hist_kernel(
    const int* __restrict__ u_idx, const int* __restrict__ i_idx,
    int* __restrict__ counts) {
  int e = blockIdx.x * 256 + threadIdx.x;
  if (e >= N_EDGES) return;
  atomicAdd(&counts[u_idx[e]], 1);            // user rows: 0..N_USERS-1
  atomicAdd(&counts[N_USERS + i_idx[e]], 1);  // item rows: N_USERS..NROWS-1
}

// per-256-block exclusive scan; block sums out
__global__ __launch_bounds__(256) void scanA_kernel(
    const int* __restrict__ counts, int* __restrict__ row_ptr,
    int* __restrict__ blksums, int n) {
  __shared__ int sh[256];
  int t = threadIdx.x;
  int i = blockIdx.x * 256 + t;
  int v = (i < n) ? counts[i] : 0;
  int x = v;
  sh[t] = x; __syncthreads();
  for (int d = 1; d < 256; d <<= 1) {
    int add = (t >= d) ? sh[t - d] : 0;
    __syncthreads();
    x += add; sh[t] = x;
    __syncthreads();
  }
  if (i < n) row_ptr[i] = x - v;  // exclusive within block
  if (t == 255) blksums[blockIdx.x] = x;
}

// single-block exclusive scan of block sums (n2 <= 1024)
__global__ __launch_bounds__(1024) void scanB_kernel(int* __restrict__ blksums, int n2) {
  __shared__ int sh[1024];
  int t = threadIdx.x;
  int v = (t < n2) ? blksums[t] : 0;
  int x = v;
  sh[t] = x; __syncthreads();
  for (int d = 1; d < 1024; d <<= 1) {
    int add = (t >= d) ? sh[t - d] : 0;
    __syncthreads();
    x += add; sh[t] = x;
    __syncthreads();
  }
  if (t < n2) blksums[t] = x - v;  // exclusive
}

// add block offsets; init cursor; set terminator
__global__ __launch_bounds__(256) void scanC_kernel(
    int* __restrict__ row_ptr, const int* __restrict__ blksums,
    int* __restrict__ cursor, int n) {
  int i = blockIdx.x * 256 + threadIdx.x;
  if (i < n) {
    int p = row_ptr[i] + blksums[i >> 8];
    row_ptr[i] = p;
    cursor[i] = p;
  }
  if (i == 0) row_ptr[n] = NDIR;
}

// scatter edges into CSR slots (order within a row is arbitrary — f32 sum
// order nondeterminism is within threshold, same as the atomic version)
__global__ __launch_bounds__(256) void scatter_csr_kernel(
    const int* __restrict__ u_idx, const int* __restrict__ i_idx,
    const float* __restrict__ w, int* __restrict__ cursor,
    int* __restrict__ csr_idx, float* __restrict__ csr_w) {
  int e = blockIdx.x * 256 + threadIdx.x;
  if (e >= N_EDGES) return;
  int u = u_idx[e], it = i_idx[e];
  float we = w[e];
  int pu = atomicAdd(&cursor[u], 1);
  csr_idx[pu] = it;   // user row gathers item rows
  csr_w[pu]   = we;
  int pi = atomicAdd(&cursor[N_USERS + it], 1);
  csr_idx[pi] = u;    // item row gathers user rows
  csr_w[pi]   = we;
}

// ---------------- per-layer gather ----------------
// One wave per destination row. lane = slot(2b) x chan16(4b); 4 edges in
// flight per iteration (4 independent 256B gathers), butterfly-reduce slots.
__global__ __launch_bounds__(256) void gather_kernel(
    const float* __restrict__ src,   // [it (3.2M) | u (6.4M)]
    float* __restrict__ dst,         // [it | u] — every row fully written
    const int* __restrict__ row_ptr,
    const int* __restrict__ csr_idx,
    const float* __restrict__ csr_w) {
  int row = blockIdx.x * 4 + (threadIdx.x >> 6);
  if (row >= NROWS) return;
  int lane = threadIdx.x & 63;
  int slot = lane >> 4;          // 0..3
  int c4   = (lane & 15) * 4;    // channel offset 0..60

  const float* table;
  float* drow;
  if (row < N_USERS) {           // user dest reads item table
    table = src;
    drow  = dst + ITEM_ELEMS + (long long)row * CH;
  } else {                       // item dest reads user table
    table = src + ITEM_ELEMS;
    drow  = dst + (long long)(row - N_USERS) * CH;
  }

  int beg = row_ptr[row], end = row_ptr[row + 1];
  float4 acc = make_float4(0.f, 0.f, 0.f, 0.f);
  for (int j = beg + slot; j < end; j += 4) {
    int   s  = csr_idx[j];
    float we = csr_w[j];
    float4 v = *(const float4*)(table + (long long)s * CH + c4);
    acc.x += we * v.x; acc.y += we * v.y;
    acc.z += we * v.z; acc.w += we * v.w;
  }
  // reduce the 4 slots (lanes L, L+16, L+32, L+48 hold the same channels)
  for (int off = 16; off < 64; off <<= 1) {
    acc.x += __shfl_xor(acc.x, off, 64);
    acc.y += __shfl_xor(acc.y, off, 64);
    acc.z += __shfl_xor(acc.z, off, 64);
    acc.w += __shfl_xor(acc.w, off, 64);
  }
  if (slot == 0) *(float4*)(drow + c4) = acc;
}

// acc = (acc + add) * s
__global__ __launch_bounds__(256) void add_scale_kernel(
    float* __restrict__ acc, const float* __restrict__ add, float s, long long n4) {
  long long i = (long long)blockIdx.x * blockDim.x + threadIdx.x;
  if (i >= n4) return;
  float4 a = ((const float4*)acc)[i];
  float4 b = ((const float4*)add)[i];
  a.x = (a.x + b.x) * s;
  a.y = (a.y + b.y) * s;
  a.z = (a.z + b.z) * s;
  a.w = (a.w + b.w) * s;
  ((float4*)acc)[i] = a;
}

// ---------------- fallback (R1 atomic path) ----------------

__global__ __launch_bounds__(256) void atomic_scatter_kernel(
    const float* __restrict__ src, float* __restrict__ dst,
    const int* __restrict__ u_idx, const int* __restrict__ i_idx,
    const float* __restrict__ w) {
  long long tid = (long long)blockIdx.x * blockDim.x + threadIdx.x;
  int edge = (int)(tid >> 4);
  if (edge >= N_EDGES) return;
  int c = ((int)tid & 15) * 4;
  int ui = u_idx[edge], ii = i_idx[edge];
  float we = w[edge];
  float4 itv = *(const float4*)(src + (long long)ii * CH + c);
  float4 uv  = *(const float4*)(src + ITEM_ELEMS + (long long)ui * CH + c);
  float* ud = dst + ITEM_ELEMS + (long long)ui * CH + c;
  float* id = dst + (long long)ii * CH + c;
  unsafeAtomicAdd(ud + 0, we * itv.x);
  unsafeAtomicAdd(ud + 1, we * itv.y);
  unsafeAtomicAdd(ud + 2, we * itv.z);
  unsafeAtomicAdd(ud + 3, we * itv.w);
  unsafeAtomicAdd(id + 0, we * uv.x);
  unsafeAtomicAdd(id + 1, we * uv.y);
  unsafeAtomicAdd(id + 2, we * uv.z);
  unsafeAtomicAdd(id + 3, we * uv.w);
}

extern "C" void kernel_launch(void* const* d_in, const int* in_sizes, int n_in,
                              void* d_out, int out_size, void* d_ws, size_t ws_size,
                              hipStream_t stream) {
  const float* user_emb = (const float*)d_in[1];
  const float* item_emb = (const float*)d_in[2];
  const int*   edges    = (const int*)d_in[3];
  const int*   u_idx    = edges;            // row 0
  const int*   i_idx    = edges + N_EDGES;  // row 1
  const float* w        = (const float*)d_in[4];

  float* out = (float*)d_out;  // [item_acc | user_acc]

  // workspace layout (4B units)
  float* buf_a   = (float*)d_ws;                 // TOT_ELEMS
  float* buf_b   = buf_a + TOT_ELEMS;            // TOT_ELEMS
  int*   csr_idx = (int*)(buf_b + TOT_ELEMS);    // NDIR
  float* csr_w   = (float*)(csr_idx + NDIR);     // NDIR
  int*   counts  = (int*)(csr_w + NDIR);         // NROWS
  int*   row_ptr = counts + NROWS;               // NROWS + 1
  int*   cursor  = row_ptr + NROWS + 1;          // NROWS
  int*   blksums = cursor + NROWS;               // 1024
  const size_t needed =
      ((size_t)2 * TOT_ELEMS + 2 * (size_t)NDIR + 3 * (size_t)NROWS + 1 + 1024) * 4;

  const size_t item_bytes = (size_t)ITEM_ELEMS * sizeof(float);
  const size_t user_bytes = (size_t)USER_ELEMS * sizeof(float);

  // init: layer-0 source and residual accumulator = input embeddings
  hipMemcpyAsync(buf_a,              item_emb, item_bytes, hipMemcpyDeviceToDevice, stream);
  hipMemcpyAsync(buf_a + ITEM_ELEMS, user_emb, user_bytes, hipMemcpyDeviceToDevice, stream);
  hipMemcpyAsync(out,                item_emb, item_bytes, hipMemcpyDeviceToDevice, stream);
  hipMemcpyAsync(out + ITEM_ELEMS,   user_emb, user_bytes, hipMemcpyDeviceToDevice, stream);

  const long long n4 = TOT_ELEMS / 4;
  const int add_blocks = (int)((n4 + 255) / 256);
  const int edge_blocks = (N_EDGES + 255) / 256;

  if (ws_size >= needed) {
    // ---- CSR build (once per call) ----
    hipMemsetAsync(counts, 0, (size_t)NROWS * sizeof(int), stream);
    hist_kernel<<<edge_blocks, 256, 0, stream>>>(u_idx, i_idx, counts);
    const int nblocksA = (NROWS + 255) / 256;  // 587 <= 1024
    scanA_kernel<<<nblocksA, 256, 0, stream>>>(counts, row_ptr, blksums, NROWS);
    scanB_kernel<<<1, 1024, 0, stream>>>(blksums, nblocksA);
    scanC_kernel<<<nblocksA, 256, 0, stream>>>(row_ptr, blksums, cursor, NROWS);
    scatter_csr_kernel<<<edge_blocks, 256, 0, stream>>>(u_idx, i_idx, w, cursor,
                                                        csr_idx, csr_w);
    // ---- layers ----
    const int gather_blocks = (NROWS + 3) / 4;  // 4 waves (rows) per block
    float* src = buf_a;
    float* dst = buf_b;
    for (int l = 0; l < LAYERS; ++l) {
      gather_kernel<<<gather_blocks, 256, 0, stream>>>(src, dst, row_ptr,
                                                       csr_idx, csr_w);
      const float s = (l == LAYERS - 1) ? (1.0f / (LAYERS + 1)) : 1.0f;
      add_scale_kernel<<<add_blocks, 256, 0, stream>>>(out, dst, s, n4);
      float* t = src; src = dst; dst = t;
    }
  } else {
    // ---- fallback: R1 atomic scatter ----
    const long long st = (long long)N_EDGES * 16;
    const int sb = (int)((st + 255) / 256);
    float* src = buf_a;
    float* dst = buf_b;
    for (int l = 0; l < LAYERS; ++l) {
      hipMemsetAsync(dst, 0, (size_t)TOT_ELEMS * sizeof(float), stream);
      atomic_scatter_kernel<<<sb, 256, 0, stream>>>(src, dst, u_idx, i_idx, w);
      const float s = (l == LAYERS - 1) ? (1.0f / (LAYERS + 1)) : 1.0f;
      add_scale_kernel<<<add_blocks, 256, 0, stream>>>(out, dst, s, n4);
      float* t = src; src = dst; dst = t;
    }
  }
}